// Round 1
// baseline (3892.886 us; speedup 1.0000x reference)
//
#include <hip/hip_runtime.h>
#include <math.h>

#define NB 8
#define NC 684
#define NH 16
#define NW 64
#define NHW 1024
#define NHID 256
#define NINP 256
#define NAD 512
#define NV 111
#define NT 36

__device__ __forceinline__ float wred_sum(float v){
  #pragma unroll
  for (int o = 32; o > 0; o >>= 1) v += __shfl_xor(v, o, 64);
  return v;
}
__device__ __forceinline__ float wred_max(float v){
  #pragma unroll
  for (int o = 32; o > 0; o >>= 1) v = fmaxf(v, __shfl_xor(v, o, 64));
  return v;
}

// ---------------- P0: dmask, msum, ys/xs (cumsum-normalized), inv dim_t, zero alpha_sum
__global__ void k_p0(const float* __restrict__ im, float* __restrict__ dmask,
                     float* __restrict__ msum, float* __restrict__ ys, float* __restrict__ xs,
                     float* __restrict__ idt, float* __restrict__ asum)
{
  const int tid = threadIdx.x; // 256 threads, 1 block
  for (int i = tid; i < NB*NHW; i += 256){
    int b = i >> 10, hw = i & 1023; int h = hw >> 6, w = hw & 63;
    dmask[i] = im[b*(256*1024) + (h*16)*1024 + (w*16)];
    asum[i] = 0.f;
  }
  if (tid < 128) idt[tid] = expf(-(float)tid * (9.210340371976184f/128.f));
  __syncthreads();
  if (tid < 8){
    float s = 0.f;
    for (int i = 0; i < NHW; i++) s += dmask[tid*NHW + i];
    msum[tid] = s;
  }
  for (int p = tid; p < NB*NW; p += 256){
    int b = p >> 6, w = p & 63;
    float tot = 0.f;
    for (int h = 0; h < NH; h++) tot += dmask[b*NHW + h*64 + w];
    float inv = 6.283185307179586f/(tot + 1e-6f);
    float run = 0.f;
    for (int h = 0; h < NH; h++){ run += dmask[b*NHW + h*64 + w]; ys[b*NHW + h*64 + w] = run*inv; }
  }
  for (int p = tid; p < NB*NH; p += 256){
    int b = p >> 4, h = p & 15;
    float tot = 0.f;
    for (int w = 0; w < NW; w++) tot += dmask[b*NHW + h*64 + w];
    float inv = 6.283185307179586f/(tot + 1e-6f);
    float run = 0.f;
    for (int w = 0; w < NW; w++){ run += dmask[b*NHW + h*64 + w]; xs[b*NHW + h*64 + w] = run*inv; }
  }
}

// ---------------- P1: masked average over spatial
__global__ void k_avg(const float* __restrict__ cnn, const float* __restrict__ dmask,
                      const float* __restrict__ msum, float* __restrict__ avg)
{
  int gid = blockIdx.x*blockDim.x + threadIdx.x;
  int gw = gid >> 6, lane = gid & 63;
  int nw = (gridDim.x*blockDim.x) >> 6;
  for (int ow = gw; ow < NB*NC; ow += nw){
    int b = ow / NC;
    const float* base = cnn + (size_t)ow * NHW;
    const float* dm = dmask + b*NHW;
    float s = 0.f;
    for (int i = lane; i < NHW; i += 64) s += base[i]*dm[i];
    s = wred_sum(s);
    if (lane == 0) avg[ow] = s / msum[b];
  }
}

// ---------------- P2: hidden0 = tanh(avg@init_W.T+b), counting_ctx
__global__ void k_init(const float* __restrict__ avg, const float* __restrict__ iW, const float* __restrict__ ib,
                       const float* __restrict__ cp, const float* __restrict__ cW, const float* __restrict__ cb,
                       float* __restrict__ hid, float* __restrict__ cctx)
{
  int gid = blockIdx.x*blockDim.x + threadIdx.x;
  int gw = gid >> 6, lane = gid & 63;
  int nw = (gridDim.x*blockDim.x) >> 6;
  for (int ow = gw; ow < 2*NB*NHID; ow += nw){
    if (ow < NB*NHID){
      int b = ow >> 8, j = ow & 255;
      float s = 0.f;
      for (int k = lane; k < NC; k += 64) s += avg[b*NC + k]*iW[j*NC + k];
      s = wred_sum(s);
      if (lane == 0) hid[ow] = tanhf(s + ib[j]);
    } else {
      int o = ow - NB*NHID; int b = o >> 8, j = o & 255;
      float s = 0.f;
      for (int k = lane; k < NV; k += 64) s += cp[b*NV + k]*cW[j*NV + k];
      s = wred_sum(s);
      if (lane == 0) cctx[o] = s + cb[j];
    }
  }
}

// ---------------- P3: trans = 1x1 conv GEMM + bias + sine pos embedding (stored [b][hw][d])
__global__ __launch_bounds__(256) void k_trans(const float* __restrict__ cnn, const float* __restrict__ ew,
     const float* __restrict__ eb, const float* __restrict__ ys, const float* __restrict__ xs,
     const float* __restrict__ idt, float* __restrict__ trans)
{
  const int mt = blockIdx.x, nt = blockIdx.y;   // 128 x 8
  const int b = mt >> 4; const int hw0 = (mt & 15) << 6;
  const int n0 = nt << 6;
  __shared__ float As[32][64];
  __shared__ float Bs[32][64];
  const int tid = threadIdx.x;
  const int tx = tid & 15, ty = tid >> 4;
  float acc[4][4];
  #pragma unroll
  for (int i=0;i<4;i++)
    #pragma unroll
    for (int j=0;j<4;j++) acc[i][j]=0.f;
  for (int c0 = 0; c0 < NC; c0 += 32){
    int kc = NC - c0; if (kc > 32) kc = 32;
    for (int idx = tid; idx < 32*64; idx += 256){
      int cc = idx >> 6, mm = idx & 63;
      As[cc][mm] = (cc < kc) ? cnn[((size_t)b*NC + c0 + cc)*NHW + hw0 + mm] : 0.f;
    }
    for (int idx = tid; idx < 32*64; idx += 256){
      int nn = idx >> 5, cc = idx & 31;
      Bs[cc][nn] = (cc < kc) ? ew[(size_t)(n0 + nn)*NC + c0 + cc] : 0.f;
    }
    __syncthreads();
    #pragma unroll
    for (int k = 0; k < 32; k++){
      float a0 = As[k][ty*4+0], a1 = As[k][ty*4+1], a2 = As[k][ty*4+2], a3 = As[k][ty*4+3];
      float b0 = Bs[k][tx*4+0], b1 = Bs[k][tx*4+1], b2 = Bs[k][tx*4+2], b3 = Bs[k][tx*4+3];
      acc[0][0]+=a0*b0; acc[0][1]+=a0*b1; acc[0][2]+=a0*b2; acc[0][3]+=a0*b3;
      acc[1][0]+=a1*b0; acc[1][1]+=a1*b1; acc[1][2]+=a1*b2; acc[1][3]+=a1*b3;
      acc[2][0]+=a2*b0; acc[2][1]+=a2*b1; acc[2][2]+=a2*b2; acc[2][3]+=a2*b3;
      acc[3][0]+=a3*b0; acc[3][1]+=a3*b1; acc[3][2]+=a3*b2; acc[3][3]+=a3*b3;
    }
    __syncthreads();
  }
  #pragma unroll
  for (int i = 0; i < 4; i++){
    int hw = hw0 + ty*4 + i;
    float ysv = ys[(b<<10) + hw], xsv = xs[(b<<10) + hw];
    #pragma unroll
    for (int j = 0; j < 4; j++){
      int d = n0 + tx*4 + j;
      float pe;
      if (d < 256){ int k = d >> 1; float arg = ysv*idt[k]; pe = (d & 1) ? cosf(arg) : sinf(arg); }
      else        { int k = (d-256) >> 1; float arg = xsv*idt[k]; pe = (d & 1) ? cosf(arg) : sinf(arg); }
      trans[(((size_t)(b<<10) + hw) << 9) + d] = acc[i][j] + eb[d] + pe;
    }
  }
}

// ---------------- P4: precompute gi (all steps) and embw (all steps)
__global__ void k_pre(const int* __restrict__ labels, const float* __restrict__ emb,
    const float* __restrict__ wih, const float* __restrict__ bih,
    const float* __restrict__ ewW, const float* __restrict__ ewb,
    float* __restrict__ gi, float* __restrict__ embw)
{
  int gid = blockIdx.x*blockDim.x + threadIdx.x;
  int gw = gid >> 6, lane = gid & 63;
  int nw = (gridDim.x*blockDim.x) >> 6;
  const int NGI = NT*NB*768;
  const int NEW_ = NT*NB*256;
  for (int ow = gw; ow < NGI + NEW_; ow += nw){
    if (ow < NGI){
      int i = ow % 768; int tb = ow / 768; int b = tb & 7, t = tb >> 3;
      int word = (t == 0) ? 1 : labels[b*NT + t - 1];
      const float* er = emb + (size_t)word*NINP;
      float s = 0.f;
      for (int k = lane; k < NINP; k += 64) s += er[k]*wih[(size_t)i*NINP + k];
      s = wred_sum(s);
      if (lane == 0) gi[ow] = s + bih[i];
    } else {
      int o = ow - NGI; int j = o & 255; int tb = o >> 8; int b = tb & 7, t = tb >> 3;
      int word = (t == 0) ? 1 : labels[b*NT + t - 1];
      const float* er = emb + (size_t)word*NINP;
      float s = 0.f;
      for (int k = lane; k < NINP; k += 64) s += er[k]*ewW[(size_t)j*NINP + k];
      s = wred_sum(s);
      if (lane == 0) embw[o] = s + ewb[j];
    }
  }
}

// ---------------- P5: fused coverage tensor  Mt[t][d] = sum_c att_weight_W[d,c]*att_conv_w[c,0,t]
__global__ void k_mt(const float* __restrict__ aw, const float* __restrict__ acw, float* __restrict__ Mt)
{
  __shared__ float col[512];
  int t = blockIdx.x; int tid = threadIdx.x;  // 121 blocks x 256
  for (int c = tid; c < 512; c += 256) col[c] = acw[(size_t)c*121 + t];
  __syncthreads();
  for (int d = tid; d < 512; d += 256){
    float s = 0.f;
    const float4* r4 = (const float4*)(aw + (size_t)d*512);
    for (int k = 0; k < 128; k++){
      float4 w = r4[k];
      s += col[k*4+0]*w.x + col[k*4+1]*w.y + col[k*4+2]*w.z + col[k*4+3]*w.w;
    }
    Mt[t*512 + d] = s;
  }
}

// ---------------- K1: GRU cell (hidden update)
__global__ void k_gru(const float* __restrict__ hin, const float* __restrict__ gi,
                      const float* __restrict__ whh, const float* __restrict__ bhh,
                      float* __restrict__ hout)
{
  int gid = blockIdx.x*blockDim.x + threadIdx.x;
  int gw = gid >> 6, lane = gid & 63;
  if (gw >= NB*NHID) return;
  int b = gw >> 8, j = gw & 255;
  const float* hrow = hin + b*NHID;
  float sr = 0.f, sz = 0.f, sn = 0.f;
  for (int k = lane; k < NHID; k += 64){
    float hv = hrow[k];
    sr += hv*whh[(size_t)(j      )*NHID + k];
    sz += hv*whh[(size_t)(j + 256)*NHID + k];
    sn += hv*whh[(size_t)(j + 512)*NHID + k];
  }
  sr = wred_sum(sr); sz = wred_sum(sz); sn = wred_sum(sn);
  if (lane == 0){
    const float* g = gi + b*768;
    float r = 1.f/(1.f + expf(-(g[j      ] + sr + bhh[j      ])));
    float z = 1.f/(1.f + expf(-(g[j + 256] + sz + bhh[j + 256])));
    float n = tanhf(g[j + 512] + r*(sn + bhh[j + 512]));
    hout[b*NHID + j] = (1.f - z)*n + z*hrow[j];
  }
}

// ---------------- K1b: query = hidden @ att_hidden_W.T + b
__global__ void k_query(const float* __restrict__ hid, const float* __restrict__ aW,
                        const float* __restrict__ ab, float* __restrict__ query)
{
  int gid = blockIdx.x*blockDim.x + threadIdx.x;
  int gw = gid >> 6, lane = gid & 63;
  int nw = (gridDim.x*blockDim.x) >> 6;
  for (int ow = gw; ow < NB*NAD; ow += nw){
    int b = ow >> 9, d = ow & 511;
    float s = 0.f;
    for (int k = lane; k < NHID; k += 64) s += hid[b*NHID + k]*aW[(size_t)d*NHID + k];
    s = wred_sum(s);
    if (lane == 0) query[ow] = s + ab[d];
  }
}

// ---------------- K2: fused coverage-stencil + tanh + energy reduction
__global__ __launch_bounds__(512) void k_energy(const float* __restrict__ asum, const float* __restrict__ Mt,
     const float* __restrict__ trans, const float* __restrict__ query, const float* __restrict__ acW,
     const float* __restrict__ acb, float* __restrict__ energy)
{
  const int whalf = blockIdx.x, h = blockIdx.y, b = blockIdx.z;
  const int tid = threadIdx.x;  // d = tid, 512 threads
  __shared__ float as[11][76];
  __shared__ float part[32][8];
  for (int idx = tid; idx < 11*74; idx += 512){
    int r = idx / 74, c = idx - r*74;
    int hi = h + r - 5, wi = c - 5;
    float v = 0.f;
    if ((unsigned)hi < 16u && (unsigned)wi < 64u) v = asum[(b<<10) + (hi<<6) + wi];
    as[r][c] = v;
  }
  __syncthreads();
  const int w0 = whalf << 5;
  float acc[32];
  #pragma unroll
  for (int i = 0; i < 32; i++) acc[i] = 0.f;
  #pragma unroll 1
  for (int ki = 0; ki < 11; ki++){
    float row[42];
    #pragma unroll
    for (int j = 0; j < 42; j++) row[j] = as[ki][w0 + j];
    const float* mrow = Mt + ki*11*512 + tid;
    #pragma unroll
    for (int kj = 0; kj < 11; kj++){
      float m = mrow[kj*512];
      #pragma unroll
      for (int w = 0; w < 32; w++) acc[w] += row[kj + w]*m;
    }
  }
  float tv[32];
  const float* tbase = trans + (((size_t)((b<<4) + h) << 6) + w0)*NAD + tid;
  #pragma unroll
  for (int w = 0; w < 32; w++) tv[w] = tbase[(size_t)w*NAD];
  const float q = query[(b<<9) + tid];
  const float wav = acW[tid];
  const int lane = tid & 63, wid = tid >> 6;
  #pragma unroll
  for (int w = 0; w < 32; w++){
    float v = wav * tanhf(q + tv[w] + acc[w]);
    v = wred_sum(v);
    if (lane == 0) part[w][wid] = v;
  }
  __syncthreads();
  if (tid < 32){
    float s = acb[0];
    #pragma unroll
    for (int i = 0; i < 8; i++) s += part[tid][i];
    energy[(b<<10) + (h<<6) + w0 + tid] = s;
  }
}

// ---------------- K3: global-max softmax + alpha + alpha_sum update (single block)
__global__ __launch_bounds__(1024) void k_softmax(const float* __restrict__ energy, const float* __restrict__ dmask,
     float* __restrict__ alpha, float* __restrict__ asum)
{
  const int tid = threadIdx.x; const int lane = tid & 63; const int wid = tid >> 6;
  __shared__ float red[16]; __shared__ float bs[8]; __shared__ float sg;
  float en[8];
  float m = -1e30f;
  #pragma unroll
  for (int k = 0; k < 8; k++){ en[k] = energy[tid + (k<<10)]; m = fmaxf(m, en[k]); }
  m = wred_max(m);
  if (lane == 0) red[wid] = m;
  __syncthreads();
  if (tid == 0){ float g = red[0]; for (int i = 1; i < 16; i++) g = fmaxf(g, red[i]); sg = g; }
  __syncthreads();
  float g = sg;
  float e[8];
  #pragma unroll
  for (int k = 0; k < 8; k++) e[k] = expf(en[k] - g)*dmask[tid + (k<<10)];
  #pragma unroll
  for (int k = 0; k < 8; k++){
    float s = wred_sum(e[k]);
    if (lane == 0) red[wid] = s;
    __syncthreads();
    if (tid == 0){ float ss = 0.f; for (int i = 0; i < 16; i++) ss += red[i]; bs[k] = ss; }
    __syncthreads();
  }
  #pragma unroll
  for (int k = 0; k < 8; k++){
    int i = tid + (k<<10);
    float a = e[k]/(bs[k] + 1e-10f);
    alpha[i] = a; asum[i] += a;
  }
}

// ---------------- K4: ctx = sum_hw alpha * cnn
__global__ void k_ctx(const float* __restrict__ alpha, const float* __restrict__ cnn, float* __restrict__ ctx)
{
  int gid = blockIdx.x*blockDim.x + threadIdx.x;
  int gw = gid >> 6, lane = gid & 63;
  int nw = (gridDim.x*blockDim.x) >> 6;
  for (int ow = gw; ow < NB*NC; ow += nw){
    int b = ow / NC;
    const float* base = cnn + (size_t)ow*NHW;
    const float* al = alpha + b*NHW;
    float s = 0.f;
    for (int i = lane; i < NHW; i += 64) s += al[i]*base[i];
    s = wred_sum(s);
    if (lane == 0) ctx[ow] = s;
  }
}

// ---------------- K56: out_state + prob (one block per batch)
__global__ __launch_bounds__(256) void k_out(const float* __restrict__ hid, const float* __restrict__ ctx,
   const float* __restrict__ embw_t, const float* __restrict__ sW, const float* __restrict__ sb,
   const float* __restrict__ cxW, const float* __restrict__ cxb, const float* __restrict__ cctx,
   const float* __restrict__ oW, const float* __restrict__ ob, float* __restrict__ out, int t)
{
  int b = blockIdx.x; int j = threadIdx.x;
  __shared__ float hs[NHID];
  __shared__ float cs[NC];
  __shared__ float os[NHID];
  hs[j] = hid[b*NHID + j];
  for (int c = j; c < NC; c += 256) cs[c] = ctx[b*NC + c];
  __syncthreads();
  float s = sb[j] + cxb[j] + embw_t[b*NHID + j] + cctx[b*NHID + j];
  const float4* w4 = (const float4*)(sW + (size_t)j*NHID);
  for (int k = 0; k < NHID/4; k++){
    float4 w = w4[k];
    s += hs[k*4]*w.x + hs[k*4+1]*w.y + hs[k*4+2]*w.z + hs[k*4+3]*w.w;
  }
  const float4* c4 = (const float4*)(cxW + (size_t)j*NC);
  for (int k = 0; k < NC/4; k++){
    float4 w = c4[k];
    s += cs[k*4]*w.x + cs[k*4+1]*w.y + cs[k*4+2]*w.z + cs[k*4+3]*w.w;
  }
  os[j] = s; __syncthreads();
  if (j < NV){
    float p = ob[j];
    const float4* o4 = (const float4*)(oW + (size_t)j*NHID);
    for (int k = 0; k < NHID/4; k++){
      float4 w = o4[k];
      p += os[k*4]*w.x + os[k*4+1]*w.y + os[k*4+2]*w.z + os[k*4+3]*w.w;
    }
    out[((size_t)b*NT + t)*NV + j] = p;
  }
}

extern "C" void kernel_launch(void* const* d_in, const int* in_sizes, int n_in,
                              void* d_out, int out_size, void* d_ws, size_t ws_size,
                              hipStream_t stream)
{
  const float* cnn  = (const float*)d_in[0];
  const float* cp   = (const float*)d_in[1];
  const float* im   = (const float*)d_in[2];
  const float* iW   = (const float*)d_in[3];
  const float* ib   = (const float*)d_in[4];
  const float* emb  = (const float*)d_in[5];
  const float* wih  = (const float*)d_in[6];
  const float* whh  = (const float*)d_in[7];
  const float* bih  = (const float*)d_in[8];
  const float* bhh  = (const float*)d_in[9];
  const float* ahW  = (const float*)d_in[10];
  const float* ahb  = (const float*)d_in[11];
  const float* acw  = (const float*)d_in[12];
  const float* awW  = (const float*)d_in[13];
  const float* acvW = (const float*)d_in[14];
  const float* acvb = (const float*)d_in[15];
  const float* ecw  = (const float*)d_in[16];
  const float* ecb  = (const float*)d_in[17];
  const float* sW   = (const float*)d_in[18];
  const float* sb   = (const float*)d_in[19];
  const float* ewW  = (const float*)d_in[20];
  const float* ewb  = (const float*)d_in[21];
  const float* cxW  = (const float*)d_in[22];
  const float* cxb  = (const float*)d_in[23];
  const float* cW   = (const float*)d_in[24];
  const float* cb   = (const float*)d_in[25];
  const float* oW   = (const float*)d_in[26];
  const float* ob   = (const float*)d_in[27];
  const int*   lab  = (const int*)d_in[28];
  float* out = (float*)d_out;
  float* ws = (float*)d_ws;

  float* dmask  = ws + 0;        // 8192
  float* ys     = ws + 8192;     // 8192
  float* xs     = ws + 16384;    // 8192
  float* idt    = ws + 24576;    // 128
  float* msum   = ws + 24704;    // 8 (+pad)
  float* avg    = ws + 24720;    // 5472
  float* cctx   = ws + 30192;    // 2048
  float* hidA   = ws + 32240;    // 2048
  float* hidB   = ws + 34288;    // 2048
  float* query  = ws + 36336;    // 4096
  float* asum   = ws + 40432;    // 8192
  float* alpha  = ws + 48624;    // 8192
  float* energy = ws + 56816;    // 8192
  float* ctx    = ws + 65008;    // 5472
  float* gi     = ws + 70480;    // 221184
  float* embw   = ws + 291664;   // 73728
  float* Mt     = ws + 365392;   // 61952
  float* trans  = ws + 427344;   // 4194304  (total ~18.5 MB)

  k_p0<<<1, 256, 0, stream>>>(im, dmask, msum, ys, xs, idt, asum);
  k_avg<<<456, 256, 0, stream>>>(cnn, dmask, msum, avg);
  k_init<<<256, 256, 0, stream>>>(avg, iW, ib, cp, cW, cb, hidA, cctx);
  k_trans<<<dim3(128, 8), 256, 0, stream>>>(cnn, ecw, ecb, ys, xs, idt, trans);
  k_pre<<<1024, 256, 0, stream>>>(lab, emb, wih, bih, ewW, ewb, gi, embw);
  k_mt<<<121, 256, 0, stream>>>(awW, acw, Mt);

  for (int t = 0; t < NT; t++){
    const float* hin = (t & 1) ? hidB : hidA;
    float* hout      = (t & 1) ? hidA : hidB;
    k_gru<<<512, 256, 0, stream>>>(hin, gi + (size_t)t*NB*768, whh, bhh, hout);
    k_query<<<256, 256, 0, stream>>>(hout, ahW, ahb, query);
    k_energy<<<dim3(2, 16, 8), 512, 0, stream>>>(asum, Mt, trans, query, acvW, acvb, energy);
    k_softmax<<<1, 1024, 0, stream>>>(energy, dmask, alpha, asum);
    k_ctx<<<342, 256, 0, stream>>>(alpha, cnn, ctx);
    k_out<<<8, 256, 0, stream>>>(hout, ctx, embw + (size_t)t*NB*NHID, sW, sb, cxW, cxb, cctx, oW, ob, out, t);
  }
}

// Round 2
// 3737.061 us; speedup vs baseline: 1.0417x; 1.0417x over previous
//
#include <hip/hip_runtime.h>
#include <math.h>

#define NB 8
#define NC 684
#define NH 16
#define NW 64
#define NHW 1024
#define NHID 256
#define NINP 256
#define NAD 512
#define NV 111
#define NT 36

__device__ __forceinline__ float wred_sum(float v){
  #pragma unroll
  for (int o = 32; o > 0; o >>= 1) v += __shfl_xor(v, o, 64);
  return v;
}
__device__ __forceinline__ float wred_max(float v){
  #pragma unroll
  for (int o = 32; o > 0; o >>= 1) v = fmaxf(v, __shfl_xor(v, o, 64));
  return v;
}

// ---------------- P0: dmask, msum, ys/xs (cumsum-normalized), inv dim_t, zero alpha_sum
__global__ void k_p0(const float* __restrict__ im, float* __restrict__ dmask,
                     float* __restrict__ msum, float* __restrict__ ys, float* __restrict__ xs,
                     float* __restrict__ idt, float* __restrict__ asum)
{
  const int tid = threadIdx.x; // 256 threads, 1 block
  for (int i = tid; i < NB*NHW; i += 256){
    int b = i >> 10, hw = i & 1023; int h = hw >> 6, w = hw & 63;
    dmask[i] = im[b*(256*1024) + (h*16)*1024 + (w*16)];
    asum[i] = 0.f;
  }
  if (tid < 128) idt[tid] = expf(-(float)tid * (9.210340371976184f/128.f));
  __syncthreads();
  if (tid < 8){
    float s = 0.f;
    for (int i = 0; i < NHW; i++) s += dmask[tid*NHW + i];
    msum[tid] = s;
  }
  for (int p = tid; p < NB*NW; p += 256){
    int b = p >> 6, w = p & 63;
    float tot = 0.f;
    for (int h = 0; h < NH; h++) tot += dmask[b*NHW + h*64 + w];
    float inv = 6.283185307179586f/(tot + 1e-6f);
    float run = 0.f;
    for (int h = 0; h < NH; h++){ run += dmask[b*NHW + h*64 + w]; ys[b*NHW + h*64 + w] = run*inv; }
  }
  for (int p = tid; p < NB*NH; p += 256){
    int b = p >> 4, h = p & 15;
    float tot = 0.f;
    for (int w = 0; w < NW; w++) tot += dmask[b*NHW + h*64 + w];
    float inv = 6.283185307179586f/(tot + 1e-6f);
    float run = 0.f;
    for (int w = 0; w < NW; w++){ run += dmask[b*NHW + h*64 + w]; xs[b*NHW + h*64 + w] = run*inv; }
  }
}

// ---------------- P1: masked average over spatial
__global__ void k_avg(const float* __restrict__ cnn, const float* __restrict__ dmask,
                      const float* __restrict__ msum, float* __restrict__ avg)
{
  int gid = blockIdx.x*blockDim.x + threadIdx.x;
  int gw = gid >> 6, lane = gid & 63;
  int nw = (gridDim.x*blockDim.x) >> 6;
  for (int ow = gw; ow < NB*NC; ow += nw){
    int b = ow / NC;
    const float* base = cnn + (size_t)ow * NHW;
    const float* dm = dmask + b*NHW;
    float s = 0.f;
    for (int i = lane; i < NHW; i += 64) s += base[i]*dm[i];
    s = wred_sum(s);
    if (lane == 0) avg[ow] = s / msum[b];
  }
}

// ---------------- P2: hidden0 = tanh(avg@init_W.T+b), counting_ctx
__global__ void k_init(const float* __restrict__ avg, const float* __restrict__ iW, const float* __restrict__ ib,
                       const float* __restrict__ cp, const float* __restrict__ cW, const float* __restrict__ cb,
                       float* __restrict__ hid, float* __restrict__ cctx)
{
  int gid = blockIdx.x*blockDim.x + threadIdx.x;
  int gw = gid >> 6, lane = gid & 63;
  int nw = (gridDim.x*blockDim.x) >> 6;
  for (int ow = gw; ow < 2*NB*NHID; ow += nw){
    if (ow < NB*NHID){
      int b = ow >> 8, j = ow & 255;
      float s = 0.f;
      for (int k = lane; k < NC; k += 64) s += avg[b*NC + k]*iW[j*NC + k];
      s = wred_sum(s);
      if (lane == 0) hid[ow] = tanhf(s + ib[j]);
    } else {
      int o = ow - NB*NHID; int b = o >> 8, j = o & 255;
      float s = 0.f;
      for (int k = lane; k < NV; k += 64) s += cp[b*NV + k]*cW[j*NV + k];
      s = wred_sum(s);
      if (lane == 0) cctx[o] = s + cb[j];
    }
  }
}

// ---------------- P3: trans = 1x1 conv GEMM + bias + sine pos embedding (stored [b][hw][d])
// Bs padded to [32][65]: kills the 32-way bank conflict on the transposed staging write.
__global__ __launch_bounds__(256) void k_trans(const float* __restrict__ cnn, const float* __restrict__ ew,
     const float* __restrict__ eb, const float* __restrict__ ys, const float* __restrict__ xs,
     const float* __restrict__ idt, float* __restrict__ trans)
{
  const int mt = blockIdx.x, nt = blockIdx.y;   // 128 x 8
  const int b = mt >> 4; const int hw0 = (mt & 15) << 6;
  const int n0 = nt << 6;
  __shared__ float As[32][64];
  __shared__ float Bs[32][65];
  const int tid = threadIdx.x;
  const int tx = tid & 15, ty = tid >> 4;
  float acc[4][4];
  #pragma unroll
  for (int i=0;i<4;i++)
    #pragma unroll
    for (int j=0;j<4;j++) acc[i][j]=0.f;
  for (int c0 = 0; c0 < NC; c0 += 32){
    int kc = NC - c0; if (kc > 32) kc = 32;
    for (int idx = tid; idx < 32*64; idx += 256){
      int cc = idx >> 6, mm = idx & 63;
      As[cc][mm] = (cc < kc) ? cnn[((size_t)b*NC + c0 + cc)*NHW + hw0 + mm] : 0.f;
    }
    for (int idx = tid; idx < 32*64; idx += 256){
      int nn = idx >> 5, cc = idx & 31;
      Bs[cc][nn] = (cc < kc) ? ew[(size_t)(n0 + nn)*NC + c0 + cc] : 0.f;
    }
    __syncthreads();
    #pragma unroll
    for (int k = 0; k < 32; k++){
      float a0 = As[k][ty*4+0], a1 = As[k][ty*4+1], a2 = As[k][ty*4+2], a3 = As[k][ty*4+3];
      float b0 = Bs[k][tx*4+0], b1 = Bs[k][tx*4+1], b2 = Bs[k][tx*4+2], b3 = Bs[k][tx*4+3];
      acc[0][0]+=a0*b0; acc[0][1]+=a0*b1; acc[0][2]+=a0*b2; acc[0][3]+=a0*b3;
      acc[1][0]+=a1*b0; acc[1][1]+=a1*b1; acc[1][2]+=a1*b2; acc[1][3]+=a1*b3;
      acc[2][0]+=a2*b0; acc[2][1]+=a2*b1; acc[2][2]+=a2*b2; acc[2][3]+=a2*b3;
      acc[3][0]+=a3*b0; acc[3][1]+=a3*b1; acc[3][2]+=a3*b2; acc[3][3]+=a3*b3;
    }
    __syncthreads();
  }
  #pragma unroll
  for (int i = 0; i < 4; i++){
    int hw = hw0 + ty*4 + i;
    float ysv = ys[(b<<10) + hw], xsv = xs[(b<<10) + hw];
    #pragma unroll
    for (int j = 0; j < 4; j++){
      int d = n0 + tx*4 + j;
      float pe;
      if (d < 256){ int k = d >> 1; float arg = ysv*idt[k]; pe = (d & 1) ? cosf(arg) : sinf(arg); }
      else        { int k = (d-256) >> 1; float arg = xsv*idt[k]; pe = (d & 1) ? cosf(arg) : sinf(arg); }
      trans[(((size_t)(b<<10) + hw) << 9) + d] = acc[i][j] + eb[d] + pe;
    }
  }
}

// ---------------- P3b: P[b][j][hw] = sum_c ctx_W[j,c] * cnn[b,c,hw]  (context projection pulled out of the loop)
__global__ __launch_bounds__(256) void k_ctxw(const float* __restrict__ cnn, const float* __restrict__ cxW,
                                              float* __restrict__ P)
{
  const int ht = blockIdx.x, jt = blockIdx.y, b = blockIdx.z;  // 16 x 4 x 8
  const int hw0 = ht << 6, j0 = jt << 6;
  __shared__ float As[32][64];   // [c][hw]
  __shared__ float Bs[32][65];   // [c][j]
  const int tid = threadIdx.x;
  const int tx = tid & 15, ty = tid >> 4;   // tx -> hw, ty -> j
  float acc[4][4];  // [j][hw]
  #pragma unroll
  for (int i=0;i<4;i++)
    #pragma unroll
    for (int j=0;j<4;j++) acc[i][j]=0.f;
  for (int c0 = 0; c0 < NC; c0 += 32){
    int kc = NC - c0; if (kc > 32) kc = 32;
    for (int idx = tid; idx < 32*64; idx += 256){
      int cc = idx >> 6, mm = idx & 63;
      As[cc][mm] = (cc < kc) ? cnn[((size_t)b*NC + c0 + cc)*NHW + hw0 + mm] : 0.f;
    }
    for (int idx = tid; idx < 32*64; idx += 256){
      int nn = idx >> 5, cc = idx & 31;
      Bs[cc][nn] = (cc < kc) ? cxW[(size_t)(j0 + nn)*NC + c0 + cc] : 0.f;
    }
    __syncthreads();
    #pragma unroll
    for (int k = 0; k < 32; k++){
      float a0 = Bs[k][ty*4+0], a1 = Bs[k][ty*4+1], a2 = Bs[k][ty*4+2], a3 = Bs[k][ty*4+3];
      float b0 = As[k][tx*4+0], b1 = As[k][tx*4+1], b2 = As[k][tx*4+2], b3 = As[k][tx*4+3];
      acc[0][0]+=a0*b0; acc[0][1]+=a0*b1; acc[0][2]+=a0*b2; acc[0][3]+=a0*b3;
      acc[1][0]+=a1*b0; acc[1][1]+=a1*b1; acc[1][2]+=a1*b2; acc[1][3]+=a1*b3;
      acc[2][0]+=a2*b0; acc[2][1]+=a2*b1; acc[2][2]+=a2*b2; acc[2][3]+=a2*b3;
      acc[3][0]+=a3*b0; acc[3][1]+=a3*b1; acc[3][2]+=a3*b2; acc[3][3]+=a3*b3;
    }
    __syncthreads();
  }
  #pragma unroll
  for (int i = 0; i < 4; i++){
    int j = j0 + ty*4 + i;
    float4 v = make_float4(acc[i][0], acc[i][1], acc[i][2], acc[i][3]);
    *(float4*)(P + ((size_t)b*NHID + j)*NHW + hw0 + tx*4) = v;
  }
}

// ---------------- P4: precompute gi (all steps) and embw (all steps)
__global__ void k_pre(const int* __restrict__ labels, const float* __restrict__ emb,
    const float* __restrict__ wih, const float* __restrict__ bih,
    const float* __restrict__ ewW, const float* __restrict__ ewb,
    float* __restrict__ gi, float* __restrict__ embw)
{
  int gid = blockIdx.x*blockDim.x + threadIdx.x;
  int gw = gid >> 6, lane = gid & 63;
  int nw = (gridDim.x*blockDim.x) >> 6;
  const int NGI = NT*NB*768;
  const int NEW_ = NT*NB*256;
  for (int ow = gw; ow < NGI + NEW_; ow += nw){
    if (ow < NGI){
      int i = ow % 768; int tb = ow / 768; int b = tb & 7, t = tb >> 3;
      int word = (t == 0) ? 1 : labels[b*NT + t - 1];
      const float* er = emb + (size_t)word*NINP;
      float s = 0.f;
      for (int k = lane; k < NINP; k += 64) s += er[k]*wih[(size_t)i*NINP + k];
      s = wred_sum(s);
      if (lane == 0) gi[ow] = s + bih[i];
    } else {
      int o = ow - NGI; int j = o & 255; int tb = o >> 8; int b = tb & 7, t = tb >> 3;
      int word = (t == 0) ? 1 : labels[b*NT + t - 1];
      const float* er = emb + (size_t)word*NINP;
      float s = 0.f;
      for (int k = lane; k < NINP; k += 64) s += er[k]*ewW[(size_t)j*NINP + k];
      s = wred_sum(s);
      if (lane == 0) embw[o] = s + ewb[j];
    }
  }
}

// ---------------- P5: fused coverage tensor  Mt[t][d] = sum_c att_weight_W[d,c]*att_conv_w[c,0,t]
__global__ void k_mt(const float* __restrict__ aw, const float* __restrict__ acw, float* __restrict__ Mt)
{
  __shared__ float col[512];
  int t = blockIdx.x; int tid = threadIdx.x;  // 121 blocks x 256
  for (int c = tid; c < 512; c += 256) col[c] = acw[(size_t)c*121 + t];
  __syncthreads();
  for (int d = tid; d < 512; d += 256){
    float s = 0.f;
    const float4* r4 = (const float4*)(aw + (size_t)d*512);
    for (int k = 0; k < 128; k++){
      float4 w = r4[k];
      s += col[k*4+0]*w.x + col[k*4+1]*w.y + col[k*4+2]*w.z + col[k*4+3]*w.w;
    }
    Mt[t*512 + d] = s;
  }
}

// ---------------- K1: GRU cell (hidden update)
__global__ void k_gru(const float* __restrict__ hin, const float* __restrict__ gi,
                      const float* __restrict__ whh, const float* __restrict__ bhh,
                      float* __restrict__ hout)
{
  int gid = blockIdx.x*blockDim.x + threadIdx.x;
  int gw = gid >> 6, lane = gid & 63;
  if (gw >= NB*NHID) return;
  int b = gw >> 8, j = gw & 255;
  const float* hrow = hin + b*NHID;
  float sr = 0.f, sz = 0.f, sn = 0.f;
  for (int k = lane; k < NHID; k += 64){
    float hv = hrow[k];
    sr += hv*whh[(size_t)(j      )*NHID + k];
    sz += hv*whh[(size_t)(j + 256)*NHID + k];
    sn += hv*whh[(size_t)(j + 512)*NHID + k];
  }
  sr = wred_sum(sr); sz = wred_sum(sz); sn = wred_sum(sn);
  if (lane == 0){
    const float* g = gi + b*768;
    float r = 1.f/(1.f + expf(-(g[j      ] + sr + bhh[j      ])));
    float z = 1.f/(1.f + expf(-(g[j + 256] + sz + bhh[j + 256])));
    float n = tanhf(g[j + 512] + r*(sn + bhh[j + 512]));
    hout[b*NHID + j] = (1.f - z)*n + z*hrow[j];
  }
}

// ---------------- K1b: query = hidden @ att_hidden_W.T + b
__global__ void k_query(const float* __restrict__ hid, const float* __restrict__ aW,
                        const float* __restrict__ ab, float* __restrict__ query)
{
  int gid = blockIdx.x*blockDim.x + threadIdx.x;
  int gw = gid >> 6, lane = gid & 63;
  int nw = (gridDim.x*blockDim.x) >> 6;
  for (int ow = gw; ow < NB*NAD; ow += nw){
    int b = ow >> 9, d = ow & 511;
    float s = 0.f;
    for (int k = lane; k < NHID; k += 64) s += hid[b*NHID + k]*aW[(size_t)d*NHID + k];
    s = wred_sum(s);
    if (lane == 0) query[ow] = s + ab[d];
  }
}

// ---------------- K2: fused coverage-stencil + tanh + energy reduction
__global__ __launch_bounds__(512) void k_energy(const float* __restrict__ asum, const float* __restrict__ Mt,
     const float* __restrict__ trans, const float* __restrict__ query, const float* __restrict__ acW,
     const float* __restrict__ acb, float* __restrict__ energy)
{
  const int whalf = blockIdx.x, h = blockIdx.y, b = blockIdx.z;
  const int tid = threadIdx.x;  // d = tid, 512 threads
  __shared__ float as[11][76];
  __shared__ float part[32][8];
  for (int idx = tid; idx < 11*74; idx += 512){
    int r = idx / 74, c = idx - r*74;
    int hi = h + r - 5, wi = c - 5;
    float v = 0.f;
    if ((unsigned)hi < 16u && (unsigned)wi < 64u) v = asum[(b<<10) + (hi<<6) + wi];
    as[r][c] = v;
  }
  __syncthreads();
  const int w0 = whalf << 5;
  float acc[32];
  #pragma unroll
  for (int i = 0; i < 32; i++) acc[i] = 0.f;
  #pragma unroll 1
  for (int ki = 0; ki < 11; ki++){
    float row[42];
    #pragma unroll
    for (int j = 0; j < 42; j++) row[j] = as[ki][w0 + j];
    const float* mrow = Mt + ki*11*512 + tid;
    #pragma unroll
    for (int kj = 0; kj < 11; kj++){
      float m = mrow[kj*512];
      #pragma unroll
      for (int w = 0; w < 32; w++) acc[w] += row[kj + w]*m;
    }
  }
  float tv[32];
  const float* tbase = trans + (((size_t)((b<<4) + h) << 6) + w0)*NAD + tid;
  #pragma unroll
  for (int w = 0; w < 32; w++) tv[w] = tbase[(size_t)w*NAD];
  const float q = query[(b<<9) + tid];
  const float wav = acW[tid];
  const int lane = tid & 63, wid = tid >> 6;
  #pragma unroll
  for (int w = 0; w < 32; w++){
    float v = wav * tanhf(q + tv[w] + acc[w]);
    v = wred_sum(v);
    if (lane == 0) part[w][wid] = v;
  }
  __syncthreads();
  if (tid < 32){
    float s = acb[0];
    #pragma unroll
    for (int i = 0; i < 8; i++) s += part[tid][i];
    energy[(b<<10) + (h<<6) + w0 + tid] = s;
  }
}

// ---------------- K3: fused per-batch softmax + alpha_sum update + ctx projection vs P
// grid (8 js, 8 b) x 256. Each block redundantly computes softmax(energy[b]) in LDS,
// block js==0 owns the asum update; each block then does 32 j-dots against P.
__global__ __launch_bounds__(256) void k_smctx(const float* __restrict__ energy, const float* __restrict__ dmask,
     const float* __restrict__ P, float* __restrict__ asum, float* __restrict__ ctxv)
{
  const int js = blockIdx.x, b = blockIdx.y;
  const int tid = threadIdx.x; const int lane = tid & 63; const int wid = tid >> 6;
  __shared__ float al[1024];
  __shared__ float red[16];
  float en[4];
  float m = -1e30f;
  #pragma unroll
  for (int k = 0; k < 4; k++){ en[k] = energy[(b<<10) + tid + (k<<8)]; m = fmaxf(m, en[k]); }
  m = wred_max(m);
  if (lane == 0) red[wid] = m;
  __syncthreads();
  if (tid == 0){ float g = fmaxf(fmaxf(red[0], red[1]), fmaxf(red[2], red[3])); red[8] = g; }
  __syncthreads();
  const float g = red[8];
  float s = 0.f;
  #pragma unroll
  for (int k = 0; k < 4; k++){
    float e = expf(en[k] - g)*dmask[(b<<10) + tid + (k<<8)];
    al[tid + (k<<8)] = e; s += e;
  }
  s = wred_sum(s);
  if (lane == 0) red[wid] = s;
  __syncthreads();
  if (tid == 0) red[9] = red[0] + red[1] + red[2] + red[3];
  __syncthreads();
  const float inv = 1.f/(red[9] + 1e-10f);
  #pragma unroll
  for (int k = 0; k < 4; k++) al[tid + (k<<8)] *= inv;
  __syncthreads();
  if (js == 0){
    #pragma unroll
    for (int k = 0; k < 4; k++){ int i = (b<<10) + tid + (k<<8); asum[i] += al[tid + (k<<8)]; }
  }
  #pragma unroll
  for (int jj = 0; jj < 8; jj++){
    int j = (js<<5) + (wid<<3) + jj;
    const float* Pr = P + ((size_t)b*NHID + j)*NHW;
    float acc = 0.f;
    for (int i = lane; i < NHW; i += 64) acc += al[i]*Pr[i];
    acc = wred_sum(acc);
    if (lane == 0) ctxv[b*NHID + j] = acc;
  }
}

// ---------------- K56: out_state + prob (one block per batch); ctx@ctxW.T arrives precomputed as ctxv
__global__ __launch_bounds__(256) void k_out(const float* __restrict__ hid, const float* __restrict__ ctxv,
   const float* __restrict__ embw_t, const float* __restrict__ sW, const float* __restrict__ sb,
   const float* __restrict__ cxb, const float* __restrict__ cctx,
   const float* __restrict__ oW, const float* __restrict__ ob, float* __restrict__ out, int t)
{
  int b = blockIdx.x; int j = threadIdx.x;
  __shared__ float hs[NHID];
  __shared__ float os[NHID];
  hs[j] = hid[b*NHID + j];
  __syncthreads();
  float s = sb[j] + cxb[j] + embw_t[b*NHID + j] + cctx[b*NHID + j] + ctxv[b*NHID + j];
  const float4* w4 = (const float4*)(sW + (size_t)j*NHID);
  for (int k = 0; k < NHID/4; k++){
    float4 w = w4[k];
    s += hs[k*4]*w.x + hs[k*4+1]*w.y + hs[k*4+2]*w.z + hs[k*4+3]*w.w;
  }
  os[j] = s; __syncthreads();
  if (j < NV){
    float p = ob[j];
    const float4* o4 = (const float4*)(oW + (size_t)j*NHID);
    for (int k = 0; k < NHID/4; k++){
      float4 w = o4[k];
      p += os[k*4]*w.x + os[k*4+1]*w.y + os[k*4+2]*w.z + os[k*4+3]*w.w;
    }
    out[((size_t)b*NT + t)*NV + j] = p;
  }
}

extern "C" void kernel_launch(void* const* d_in, const int* in_sizes, int n_in,
                              void* d_out, int out_size, void* d_ws, size_t ws_size,
                              hipStream_t stream)
{
  const float* cnn  = (const float*)d_in[0];
  const float* cp   = (const float*)d_in[1];
  const float* im   = (const float*)d_in[2];
  const float* iW   = (const float*)d_in[3];
  const float* ib   = (const float*)d_in[4];
  const float* emb  = (const float*)d_in[5];
  const float* wih  = (const float*)d_in[6];
  const float* whh  = (const float*)d_in[7];
  const float* bih  = (const float*)d_in[8];
  const float* bhh  = (const float*)d_in[9];
  const float* ahW  = (const float*)d_in[10];
  const float* ahb  = (const float*)d_in[11];
  const float* acw  = (const float*)d_in[12];
  const float* awW  = (const float*)d_in[13];
  const float* acvW = (const float*)d_in[14];
  const float* acvb = (const float*)d_in[15];
  const float* ecw  = (const float*)d_in[16];
  const float* ecb  = (const float*)d_in[17];
  const float* sW   = (const float*)d_in[18];
  const float* sb   = (const float*)d_in[19];
  const float* ewW  = (const float*)d_in[20];
  const float* ewb  = (const float*)d_in[21];
  const float* cxW  = (const float*)d_in[22];
  const float* cxb  = (const float*)d_in[23];
  const float* cW   = (const float*)d_in[24];
  const float* cb   = (const float*)d_in[25];
  const float* oW   = (const float*)d_in[26];
  const float* ob   = (const float*)d_in[27];
  const int*   lab  = (const int*)d_in[28];
  float* out = (float*)d_out;
  float* ws = (float*)d_ws;

  float* dmask  = ws + 0;        // 8192
  float* ys     = ws + 8192;     // 8192
  float* xs     = ws + 16384;    // 8192
  float* idt    = ws + 24576;    // 128
  float* msum   = ws + 24704;    // 16
  float* avg    = ws + 24720;    // 5472
  float* cctx   = ws + 30192;    // 2048
  float* hidA   = ws + 32240;    // 2048
  float* hidB   = ws + 34288;    // 2048
  float* query  = ws + 36336;    // 4096
  float* asum   = ws + 40432;    // 8192
  float* energy = ws + 48624;    // 8192
  float* ctxv   = ws + 56816;    // 2048
  float* gi     = ws + 58864;    // 221184
  float* embw   = ws + 280048;   // 73728
  float* Mt     = ws + 353776;   // 61952
  float* trans  = ws + 415728;   // 4194304
  float* P      = ws + 4610032;  // 2097152  (total ~26.8 MB)

  k_p0<<<1, 256, 0, stream>>>(im, dmask, msum, ys, xs, idt, asum);
  k_avg<<<456, 256, 0, stream>>>(cnn, dmask, msum, avg);
  k_init<<<256, 256, 0, stream>>>(avg, iW, ib, cp, cW, cb, hidA, cctx);
  k_trans<<<dim3(128, 8), 256, 0, stream>>>(cnn, ecw, ecb, ys, xs, idt, trans);
  k_ctxw<<<dim3(16, 4, 8), 256, 0, stream>>>(cnn, cxW, P);
  k_pre<<<1024, 256, 0, stream>>>(lab, emb, wih, bih, ewW, ewb, gi, embw);
  k_mt<<<121, 256, 0, stream>>>(awW, acw, Mt);

  for (int t = 0; t < NT; t++){
    const float* hin = (t & 1) ? hidB : hidA;
    float* hout      = (t & 1) ? hidA : hidB;
    k_gru<<<512, 256, 0, stream>>>(hin, gi + (size_t)t*NB*768, whh, bhh, hout);
    k_query<<<256, 256, 0, stream>>>(hout, ahW, ahb, query);
    k_energy<<<dim3(2, 16, 8), 512, 0, stream>>>(asum, Mt, trans, query, acvW, acvb, energy);
    k_smctx<<<dim3(8, 8), 256, 0, stream>>>(energy, dmask, P, asum, ctxv);
    k_out<<<8, 256, 0, stream>>>(hout, ctxv, embw + (size_t)t*NB*NHID, sW, sb, cxb, cctx, oW, ob, out, t);
  }
}